// Round 1
// baseline (275.659 us; speedup 1.0000x reference)
//
#include <hip/hip_runtime.h>
#include <math.h>

#define EMBS_DIM 300
#define SCAN_BLOCK 1024
#define VEC 4
#define CHUNK (SCAN_BLOCK * VEC)   // 4096 samples per scan iteration

// Kernel 1: build the 300-element noise vector.
// Single block; chunked scan over samples with block-wide prefix sum of the
// acceptance mask. float4 loads, 4 samples/thread: expected acceptances in
// the first 4096-sample chunk = 473 >= 300, so the loop almost always
// terminates after ONE iteration (loop kept for data-independence).
__global__ __launch_bounds__(SCAN_BLOCK) void build_noise_kernel(
    const float* __restrict__ sgn, const float* __restrict__ u, int n,
    float* __restrict__ noise, float scale, float A)
{
    __shared__ int s_wave_tot[SCAN_BLOCK / 64];
    const int tid  = threadIdx.x;
    const int lane = tid & 63;
    const int wave = tid >> 6;
    const int nwaves = SCAN_BLOCK / 64;

    // Zero-init noise (d_ws is poisoned before every launch); if fewer than
    // 300 samples are accepted the tail must be 0.
    for (int j = tid; j < EMBS_DIM; j += SCAN_BLOCK) noise[j] = 0.0f;
    __syncthreads();

    int base = 0;  // accepted-so-far; uniform across block
    for (int i0 = 0; i0 < n; i0 += CHUNK) {
        const int i = i0 + tid * VEC;   // thread-major sample order
        float r[VEC];
        int   m[VEC];
        if (i + VEC - 1 < n) {
            // 16B-aligned: i0 % 4096 == 0, tid*VEC % 4 == 0, alloc base aligned.
            const float4 sv = *(const float4*)(sgn + i);
            const float4 uv = *(const float4*)(u + i);
            const float ss[VEC] = {sv.x, sv.y, sv.z, sv.w};
            const float us[VEC] = {uv.x, uv.y, uv.z, uv.w};
            #pragma unroll
            for (int k = 0; k < VEC; ++k) {
                const float s  = ss[k];
                const float sg = (s > 0.0f) ? 1.0f : ((s < 0.0f) ? -1.0f : 0.0f);
                r[k] = (-scale * sg) * logf(us[k]);   // same op order as before
                m[k] = (r[k] >= -A && r[k] <= A) ? 1 : 0;
            }
        } else {
            #pragma unroll
            for (int k = 0; k < VEC; ++k) {
                r[k] = 0.0f; m[k] = 0;
                if (i + k < n) {
                    const float s  = sgn[i + k];
                    const float sg = (s > 0.0f) ? 1.0f : ((s < 0.0f) ? -1.0f : 0.0f);
                    r[k] = (-scale * sg) * logf(u[i + k]);
                    m[k] = (r[k] >= -A && r[k] <= A) ? 1 : 0;
                }
            }
        }

        // Block-wide exclusive prefix over thread-major sample order.
        // bal[k] = mask of threads whose k-th sample is accepted. The count of
        // accepted samples in lanes < lane (all 4 slots) is sum_k popc(bal[k]&lt).
        unsigned long long bal[VEC];
        #pragma unroll
        for (int k = 0; k < VEC; ++k) bal[k] = __ballot(m[k]);
        const unsigned long long ltm = (1ull << lane) - 1ull;
        int excl = 0, wtot = 0;
        #pragma unroll
        for (int k = 0; k < VEC; ++k) {
            excl += __popcll(bal[k] & ltm);
            wtot += __popcll(bal[k]);
        }
        if (lane == 0) s_wave_tot[wave] = wtot;
        __syncthreads();
        int woff = 0, tot = 0;
        #pragma unroll
        for (int w = 0; w < nwaves; ++w) {
            const int t = s_wave_tot[w];
            if (w < wave) woff += t;
            tot += t;
        }
        int pos = base + woff + excl;
        #pragma unroll
        for (int k = 0; k < VEC; ++k) {
            if (m[k]) {
                if (pos < EMBS_DIM) noise[pos] = r[k];
                ++pos;
            }
        }
        base += tot;
        __syncthreads();  // protect s_wave_tot before next chunk overwrites
        if (base >= EMBS_DIM) break;
    }
}

// Kernel 2: out = embs + broadcast(noise). 300 f32 per row = 75 float4 per
// row. Pure HBM-bound streaming add; 4 float4 (64 B) per thread, block-strided
// so each instruction stays fully coalesced and each thread has 4 loads in
// flight (MLP for the streaming read).
#define ADD_BLOCK  256
#define ADD_UNROLL 4
__global__ __launch_bounds__(ADD_BLOCK) void add_noise_kernel(
    const float4* __restrict__ embs, const float4* __restrict__ noise4,
    float4* __restrict__ out, int total4)
{
    const int base = blockIdx.x * (ADD_BLOCK * ADD_UNROLL) + threadIdx.x;
    float4 e[ADD_UNROLL];
    #pragma unroll
    for (int k = 0; k < ADD_UNROLL; ++k) {
        const int idx = base + k * ADD_BLOCK;
        if (idx < total4) e[k] = embs[idx];
    }
    #pragma unroll
    for (int k = 0; k < ADD_UNROLL; ++k) {
        const int idx = base + k * ADD_BLOCK;
        if (idx < total4) {
            const float4 nv = noise4[idx % (EMBS_DIM / 4)];  // 1200 B, L1-hot
            float4 o;
            o.x = e[k].x + nv.x;
            o.y = e[k].y + nv.y;
            o.z = e[k].z + nv.z;
            o.w = e[k].w + nv.w;
            out[idx] = o;
        }
    }
}

extern "C" void kernel_launch(void* const* d_in, const int* in_sizes, int n_in,
                              void* d_out, int out_size, void* d_ws, size_t ws_size,
                              hipStream_t stream)
{
    const float* embs = (const float*)d_in[0];
    const float* sgn  = (const float*)d_in[1];
    const float* u    = (const float*)d_in[2];
    float* out   = (float*)d_out;
    float* noise = (float*)d_ws;      // 300 floats, 16B-aligned (alloc base)

    const int n = in_sizes[1];        // N_SAMPLES = 1,000,000

    // Match Python: _SCALE/_A computed in float64, cast to float32.
    const double scaled = 2.0 * 0.005 * sqrt(300.0) / 1.0;
    const double Ad     = -scaled * log(1.0 - 2.0 * 1.0 / sqrt(300.0));
    const float scale = (float)scaled;
    const float A     = (float)Ad;

    build_noise_kernel<<<1, SCAN_BLOCK, 0, stream>>>(sgn, u, n, noise, scale, A);

    const int total4 = out_size / 4;                              // 9,830,400
    const int blocks = (total4 + ADD_BLOCK * ADD_UNROLL - 1) / (ADD_BLOCK * ADD_UNROLL);
    add_noise_kernel<<<blocks, ADD_BLOCK, 0, stream>>>(
        (const float4*)embs, (const float4*)noise, (float4*)out, total4);
}